// Round 1
// baseline (155.650 us; speedup 1.0000x reference)
//
#include <hip/hip_runtime.h>

#define LSZ 1024
#define EPS 1e-8f
#define NBLK 2048
#define SPT 2                      // sites per thread
#define STRIDE (NBLK * 256)        // 524288 threads

struct c32 { float re, im; };

__device__ __forceinline__ c32 cmul(c32 a, c32 b) {
    return { a.re * b.re - a.im * b.im, a.re * b.im + a.im * b.re };
}
// a * conj(b)
__device__ __forceinline__ c32 cmulc(c32 a, c32 b) {
    return { a.re * b.re + a.im * b.im, a.im * b.re - a.re * b.im };
}
__device__ __forceinline__ c32 cadd(c32 a, c32 b) {
    return { a.re + b.re, a.im + b.im };
}

// g = cos(n) I + i sinc(n) (theta . sigma). Native sin/cos/rcp: theta norms
// are <= ~7 (3 gaussians), safely in fast range; error ~1e-6 << 8e-2 thresh.
__device__ __forceinline__ void make_g(float tx, float ty, float tz, c32 g[2][2]) {
    float n2 = tx * tx + ty * ty + tz * tz;
    float n  = __builtin_amdgcn_sqrtf(n2);
    float cc = __cosf(n);
    float sn = __sinf(n);
    float s  = (n > EPS) ? (sn * __builtin_amdgcn_rcpf(n)) : 1.0f;
    float a1 = s * tx, a2 = s * ty, a3 = s * tz;
    g[0][0] = {  cc,  a3 };
    g[0][1] = {  a2,  a1 };
    g[1][0] = { -a2,  a1 };
    g[1][1] = {  cc, -a3 };
}

// Ut = g @ M @ gn^dagger ; return sum |P - Ut|^2 over the 4 entries
__device__ __forceinline__ float site_mu_loss(const c32 g[2][2], const c32 gn[2][2],
                                              float4 m0, float4 m1,
                                              float4 p0, float4 p1) {
    c32 M[2][2] = { { { m0.x, m0.y }, { m0.z, m0.w } },
                    { { m1.x, m1.y }, { m1.z, m1.w } } };
    c32 P[2][2] = { { { p0.x, p0.y }, { p0.z, p0.w } },
                    { { p1.x, p1.y }, { p1.z, p1.w } } };
    c32 T[2][2];
#pragma unroll
    for (int a = 0; a < 2; ++a)
#pragma unroll
        for (int cc = 0; cc < 2; ++cc)
            T[a][cc] = cadd(cmul(g[a][0], M[0][cc]), cmul(g[a][1], M[1][cc]));

    float acc = 0.0f;
#pragma unroll
    for (int a = 0; a < 2; ++a)
#pragma unroll
        for (int d = 0; d < 2; ++d) {
            c32 ut = cadd(cmulc(T[a][0], gn[d][0]), cmulc(T[a][1], gn[d][1]));
            float dr = P[a][d].re - ut.re;
            float di = P[a][d].im - ut.im;
            acc += dr * dr + di * di;
        }
    return acc;
}

// Low-register site loss: two mu-phases so peak live set stays under the
// 64-VGPR occupancy cliff (gfx950 waves/SIMD halve at 64/128/256 regs).
// Phase A: theta loads -> g, gx; mu=0 U loads -> loss0.
// Phase B: gy (from cached tc), mu=1 U loads -> loss1.
__device__ __forceinline__ float site_loss(int idx,
                                           const float* __restrict__ theta,
                                           const float* __restrict__ U_pred,
                                           const float* __restrict__ U_true) {
    int x = idx >> 10, y = idx & (LSZ - 1);
    int xp = (x + 1) & (LSZ - 1), yp = (y + 1) & (LSZ - 1);

    const float* ta = theta + 3 * (x  * LSZ + y);
    const float* tb = theta + 3 * (xp * LSZ + y);
    const float* tc = theta + 3 * (x  * LSZ + yp);
    const float4* Ut4 = (const float4*)U_true + (size_t)idx * 4;
    const float4* Up4 = (const float4*)U_pred + (size_t)idx * 4;

    // Issue theta + mu=0 U loads; keep mu=1 loads in source after loss0 so the
    // register allocator (capped at 64 by launch_bounds) has room to schedule.
    float a0 = ta[0], a1 = ta[1], a2 = ta[2];
    float b0 = tb[0], b1 = tb[1], b2 = tb[2];
    float c0 = tc[0], c1 = tc[1], c2 = tc[2];
    float4 t0 = Ut4[0], t1 = Ut4[1];
    float4 p0 = Up4[0], p1 = Up4[1];

    c32 g[2][2], gn[2][2];
    make_g(a0, a1, a2, g);
    make_g(b0, b1, b2, gn);
    float acc = site_mu_loss(g, gn, t0, t1, p0, p1);   // mu = 0

    float4 t2 = Ut4[2], t3 = Ut4[3];
    float4 p2 = Up4[2], p3 = Up4[3];
    make_g(c0, c1, c2, gn);
    acc += site_mu_loss(g, gn, t2, t3, p2, p3);        // mu = 1
    return acc;
}

// Pure-TLP streaming kernel. Prior variants all ran at 16 resident waves/CU
// (1024-block grids: grid-limited; one-shot: VGPR>64 limited) and pinned at
// ~49 us = 45% of stream rate. 2048 blocks (8/CU) x launch_bounds(256,8)
// (forces <=64 VGPR) doubles resident waves to 32/CU; at high occupancy TLP
// hides the L2/L3/HBM latency without software pipelining.
__global__ __launch_bounds__(256, 8) void gauge_loss_kernel(
    const float* __restrict__ theta,
    const float* __restrict__ U_pred,
    const float* __restrict__ U_true,
    float* __restrict__ partial) {
    const int tid = blockIdx.x * 256 + threadIdx.x;

    float acc = 0.0f;
#pragma unroll
    for (int s = 0; s < SPT; ++s)
        acc += site_loss(tid + s * STRIDE, theta, U_pred, U_true);

    // fold: mean over 4 entries (1/4) and final /(L*L*2)
    acc *= (1.0f / (8.0f * (float)LSZ * (float)LSZ));

    // wave (64-lane) shuffle reduction
#pragma unroll
    for (int off = 32; off > 0; off >>= 1)
        acc += __shfl_down(acc, off, 64);

    __shared__ float wave_sums[4];
    int lane = threadIdx.x & 63;
    int wave = threadIdx.x >> 6;
    if (lane == 0) wave_sums[wave] = acc;
    __syncthreads();
    if (threadIdx.x == 0)
        partial[blockIdx.x] = wave_sums[0] + wave_sums[1] + wave_sums[2] + wave_sums[3];
}

__global__ __launch_bounds__(256) void reduce_kernel(const float* __restrict__ partial,
                                                     float* __restrict__ out) {
    float s = 0.0f;
#pragma unroll
    for (int i = 0; i < NBLK / 256; ++i)
        s += partial[i * 256 + threadIdx.x];

#pragma unroll
    for (int off = 32; off > 0; off >>= 1)
        s += __shfl_down(s, off, 64);

    __shared__ float wave_sums[4];
    int lane = threadIdx.x & 63;
    int wave = threadIdx.x >> 6;
    if (lane == 0) wave_sums[wave] = s;
    __syncthreads();
    if (threadIdx.x == 0)
        out[0] = wave_sums[0] + wave_sums[1] + wave_sums[2] + wave_sums[3];
}

extern "C" void kernel_launch(void* const* d_in, const int* in_sizes, int n_in,
                              void* d_out, int out_size, void* d_ws, size_t ws_size,
                              hipStream_t stream) {
    const float* theta  = (const float*)d_in[0];
    const float* U_pred = (const float*)d_in[1];
    const float* U_true = (const float*)d_in[2];
    float* out = (float*)d_out;
    float* partial = (float*)d_ws;  // NBLK floats

    gauge_loss_kernel<<<NBLK, 256, 0, stream>>>(theta, U_pred, U_true, partial);
    reduce_kernel<<<1, 256, 0, stream>>>(partial, out);
}